// Round 10
// baseline (4017.295 us; speedup 1.0000x reference)
//
#include <hip/hip_runtime.h>

// ---------------------------------------------------------------------------
// Head_87033217286245 — Round 10: INSTRUMENTATION ROUND. R9 pipeline verbatim
// (absmax 0) + four probe kernels with internal x8/x16 repetition so their
// dispatch durations exceed the 158us harness fills and surface in top-5
// rocprof WITH counters. Decode: per-kernel cost = probe_dur / reps.
// ---------------------------------------------------------------------------

typedef float f32x4 __attribute__((ext_vector_type(4)));

#define B_      128
#define L_      512
#define NSPANS  3
#define HIDDEN  512
#define DG      4096

__device__ __forceinline__ float dp4(f32x4 a, f32x4 b) {
    return a.x*b.x + a.y*b.y + a.z*b.z + a.w*b.w;
}

// ---- k0: u_t[k] = Sum_o W[o,k,t]*aw[o];  Wt2[t][k][o];  fcT[i][j]
__global__ __launch_bounds__(256)
void prep_kernel(const float* __restrict__ cw, const float* __restrict__ aw,
                 const float* __restrict__ fcw,
                 float* __restrict__ u, float* __restrict__ Wt2,
                 float* __restrict__ fcT) {
    const int idx = blockIdx.x * 256 + threadIdx.x;
    if (idx < 3072) {
        const int t = idx >> 10, k = idx & 1023;
        float s = 0.f;
        #pragma unroll 8
        for (int o = 0; o < 64; ++o)
            s += cw[(size_t)(o * 1024 + k) * 3 + t] * aw[o];
        u[idx] = s;
    }
    for (int i = idx; i < 196608; i += 24576) {
        const int o = i & 63, k = (i >> 6) & 1023, t = i >> 16;
        Wt2[i] = cw[(size_t)(o * 1024 + k) * 3 + t];
    }
    for (int i = idx; i < 98304; i += 24576) {
        const int j = i & 511, r = i >> 9;
        fcT[i] = fcw[(size_t)j * 192 + r];
    }
}

// ---- k1: dots (R9 verbatim)
__global__ __launch_bounds__(256, 4)
void dots_kernel(const float* __restrict__ X, const float* __restrict__ u,
                 float* __restrict__ d0, float* __restrict__ d1,
                 float* __restrict__ d2) {
    __shared__ float red[12];
    const int tid = threadIdx.x, lane = tid & 63, wv = tid >> 6;
    const f32x4 u0 = *(const f32x4*)(u + tid * 4);
    const f32x4 u1 = *(const f32x4*)(u + 1024 + tid * 4);
    const f32x4 u2 = *(const f32x4*)(u + 2048 + tid * 4);

    int row = blockIdx.x;
    f32x4 xA = *(const f32x4*)(X + (size_t)row * 1024 + tid * 4);
    f32x4 xB;
    #pragma unroll 4
    for (int i = 0; i < 16; ++i) {
        const int nrow = row + DG;
        if (i + 1 < 16)
            xB = *(const f32x4*)(X + (size_t)nrow * 1024 + tid * 4);
        float p0 = dp4(xA, u0), p1 = dp4(xA, u1), p2 = dp4(xA, u2);
        #pragma unroll
        for (int off = 32; off >= 1; off >>= 1) {
            p0 += __shfl_xor(p0, off);
            p1 += __shfl_xor(p1, off);
            p2 += __shfl_xor(p2, off);
        }
        if (lane == 0) {
            red[wv * 3 + 0] = p0; red[wv * 3 + 1] = p1; red[wv * 3 + 2] = p2;
        }
        __syncthreads();
        if (tid < 3) {
            const float s = red[tid] + red[3 + tid] + red[6 + tid] + red[9 + tid];
            float* dst = (tid == 0) ? d0 : (tid == 1) ? d1 : d2;
            dst[row] = s;
        }
        __syncthreads();
        xA = xB;
        row = nrow;
    }
}

// ---- k2: coef (R9 verbatim)
__global__ __launch_bounds__(256)
void coef_kernel(const float* __restrict__ d0, const float* __restrict__ d1,
                 const float* __restrict__ d2, const int* __restrict__ offs,
                 float* __restrict__ C, float* __restrict__ Zv) {
    __shared__ float lg[L_];
    __shared__ float red[4];
    const int b = blockIdx.x, tid = threadIdx.x, lane = tid & 63, wv = tid >> 6;
    const size_t g = (size_t)b * L_;

    for (int l = tid; l < L_; l += 256) {
        float v = d1[g + l];
        if (l >= 1)      v += d0[g + l - 1];
        if (l <= L_ - 2) v += d2[g + l + 1];
        lg[l] = v;
    }
    __syncthreads();

    float mxr[3]; int str[3], enr[3];
    for (int s = 0; s < 3; ++s) {
        const int st = offs[b * 6 + s * 2], en = offs[b * 6 + s * 2 + 1];
        str[s] = st; enr[s] = en;
        float mx = -1e30f;
        for (int l = st + tid; l <= en; l += 256) mx = fmaxf(mx, lg[l]);
        #pragma unroll
        for (int off = 32; off >= 1; off >>= 1) mx = fmaxf(mx, __shfl_xor(mx, off));
        if (lane == 0) red[wv] = mx;
        __syncthreads();
        mx = fmaxf(fmaxf(red[0], red[1]), fmaxf(red[2], red[3]));
        __syncthreads();
        float sm = 0.f;
        for (int l = st + tid; l <= en; l += 256) sm += __expf(lg[l] - mx);
        #pragma unroll
        for (int off = 32; off >= 1; off >>= 1) sm += __shfl_xor(sm, off);
        if (lane == 0) red[wv] = sm;
        __syncthreads();
        if (tid == 0) Zv[b * 3 + s] = red[0] + red[1] + red[2] + red[3];
        __syncthreads();
        mxr[s] = mx;
    }

    for (int m = tid; m < L_; m += 256) {
        f32x4 c[3];
        #pragma unroll
        for (int s = 0; s < 3; ++s) {
            #pragma unroll
            for (int t = 0; t < 3; ++t) {
                const int l  = m + 1 - t;
                const int li = min(max(l, 0), L_ - 1);
                c[s][t] = (l >= str[s] && l <= enr[s]) ? __expf(lg[li] - mxr[s]) : 0.f;
            }
            c[s][3] = 0.f;
        }
        float* cp = C + ((size_t)(g + m)) * 12;
        *(f32x4*)(cp)     = c[0];
        *(f32x4*)(cp + 4) = c[1];
        *(f32x4*)(cp + 8) = c[2];
    }
}

// ---- k3: span_acc (R9 verbatim)
__global__ __launch_bounds__(256, 4)
void span_acc_kernel(const float* __restrict__ X, const float* __restrict__ C,
                     float* __restrict__ part) {
    __shared__ float cs[256 * 12];
    __shared__ unsigned char flg[256];
    __shared__ int wany[4];
    __shared__ float rbuf[256 * 4];

    const int blk = blockIdx.x;
    const int b = blk >> 3, p = blk & 7;
    const int q = p >> 1, h = p & 1;
    const int tid = threadIdx.x, lane = tid & 63, wv = tid >> 6;
    float* pb = part + (size_t)blk * 2304;

    {
        const float* cp = C + ((size_t)b * 512 + h * 256) * 12;
        #pragma unroll
        for (int w = 0; w < 3; ++w)
            *(f32x4*)&cs[(tid + w * 256) * 4] = *(const f32x4*)(cp + (tid + w * 256) * 4);
    }
    __syncthreads();
    {
        const float* cr = &cs[tid * 12];
        float s = 0.f;
        #pragma unroll
        for (int j = 0; j < 12; ++j) s += fabsf(cr[j]);
        const bool f = (s != 0.f);
        flg[tid] = f ? 1 : 0;
        const unsigned long long m = __ballot(f);
        if (lane == 0) wany[wv] = (m != 0ull) ? 1 : 0;
    }
    __syncthreads();
    if ((wany[0] | wany[1] | wany[2] | wany[3]) == 0) {
        for (int i = tid; i < 2304; i += 256) pb[i] = 0.f;
        return;
    }

    f32x4 acc[9];
    #pragma unroll
    for (int a = 0; a < 9; ++a) acc[a] = (f32x4){0.f, 0.f, 0.f, 0.f};

    const float* Xw = X + ((size_t)b * 512 + h * 256 + wv * 64) * 1024 + q * 256 + lane * 4;
    const int rbase = wv * 64;

    for (int c = 0; c < 16; ++c) {
        const int r0 = rbase + c * 4;
        if ((flg[r0] | flg[r0 + 1] | flg[r0 + 2] | flg[r0 + 3]) == 0) continue;
        f32x4 x0 = *(const f32x4*)(Xw + (size_t)(c * 4 + 0) * 1024);
        f32x4 x1 = *(const f32x4*)(Xw + (size_t)(c * 4 + 1) * 1024);
        f32x4 x2 = *(const f32x4*)(Xw + (size_t)(c * 4 + 2) * 1024);
        f32x4 x3 = *(const f32x4*)(Xw + (size_t)(c * 4 + 3) * 1024);
        #define ROWFMA(xr, rr) { \
            f32x4 c0 = *(const f32x4*)&cs[(rr) * 12]; \
            f32x4 c1 = *(const f32x4*)&cs[(rr) * 12 + 4]; \
            f32x4 c2 = *(const f32x4*)&cs[(rr) * 12 + 8]; \
            acc[0] += c0.x * xr; acc[1] += c0.y * xr; acc[2] += c0.z * xr; \
            acc[3] += c1.x * xr; acc[4] += c1.y * xr; acc[5] += c1.z * xr; \
            acc[6] += c2.x * xr; acc[7] += c2.y * xr; acc[8] += c2.z * xr; }
        ROWFMA(x0, r0)
        ROWFMA(x1, r0 + 1)
        ROWFMA(x2, r0 + 2)
        ROWFMA(x3, r0 + 3)
        #undef ROWFMA
    }

    #pragma unroll
    for (int a = 0; a < 9; ++a) {
        __syncthreads();
        *(f32x4*)&rbuf[tid * 4] = acc[a];
        __syncthreads();
        if (tid < 64) {
            f32x4 s = *(const f32x4*)&rbuf[tid * 4];
            s += *(const f32x4*)&rbuf[(64 + tid) * 4];
            s += *(const f32x4*)&rbuf[(128 + tid) * 4];
            s += *(const f32x4*)&rbuf[(192 + tid) * 4];
            *(f32x4*)(pb + a * 256 + tid * 4) = s;
        }
    }
}

// ---- k4: head (R9 verbatim)
__global__ __launch_bounds__(256)
void head_kernel(const float* __restrict__ part, const float* __restrict__ Zv,
                 const float* __restrict__ Wt2, const float* __restrict__ cb,
                 const float* __restrict__ fcT,
                 const float* __restrict__ in_urls, const float* __restrict__ other,
                 const float* __restrict__ bn1_g, const float* __restrict__ bn1_b,
                 const float* __restrict__ bn1_m, const float* __restrict__ bn1_v,
                 const float* __restrict__ fc_b,
                 const float* __restrict__ bn2_g, const float* __restrict__ bn2_b,
                 const float* __restrict__ bn2_m, const float* __restrict__ bn2_v,
                 const float* __restrict__ last_w, const float* __restrict__ last_b,
                 float* __restrict__ out) {
    __shared__ float yb[9 * 1024];
    __shared__ float emb[NSPANS * 64];
    __shared__ float hbuf[HIDDEN];

    const int b = blockIdx.x, tid = threadIdx.x, lane = tid & 63, wv = tid >> 6;

    {
        const int q = tid >> 6, pos = (tid & 63) * 4;
        const float* p0 = part + (size_t)(b * 8 + q * 2 + 0) * 2304 + pos;
        const float* p1 = part + (size_t)(b * 8 + q * 2 + 1) * 2304 + pos;
        #pragma unroll
        for (int i = 0; i < 9; ++i) {
            f32x4 v = *(const f32x4*)(p0 + i * 256) + *(const f32x4*)(p1 + i * 256);
            *(f32x4*)&yb[i * 1024 + q * 256 + pos] = v;
        }
    }
    __syncthreads();

    if (tid < 192) {
        const int s = tid >> 6, o = tid & 63;
        float a0 = 0.f, a1 = 0.f, a2 = 0.f, a3 = 0.f;
        #pragma unroll
        for (int t = 0; t < 3; ++t) {
            const float* wp = Wt2 + (size_t)t * 65536 + o;
            const float* yp = &yb[(s * 3 + t) * 1024];
            for (int k = 0; k < 1024; k += 4) {
                a0 += wp[(size_t)(k + 0) * 64] * yp[k + 0];
                a1 += wp[(size_t)(k + 1) * 64] * yp[k + 1];
                a2 += wp[(size_t)(k + 2) * 64] * yp[k + 2];
                a3 += wp[(size_t)(k + 3) * 64] * yp[k + 3];
            }
        }
        const float ev = (a0 + a1 + a2 + a3) / Zv[b * 3 + s] + cb[o];
        emb[tid] = (ev - bn1_m[tid]) * rsqrtf(bn1_v[tid] + 1e-5f) * bn1_g[tid] + bn1_b[tid];
    }
    __syncthreads();

    #pragma unroll
    for (int qq = 0; qq < 2; ++qq) {
        const int j = tid + qq * 256;
        float s = fc_b[j];
        #pragma unroll 4
        for (int i = 0; i < NSPANS * 64; ++i)
            s += fcT[(size_t)i * 512 + j] * emb[i];
        s = fmaxf(s, 0.f);
        hbuf[j] = (s - bn2_m[j]) * rsqrtf(bn2_v[j] + 1e-5f) * bn2_g[j] + bn2_b[j];
    }
    __syncthreads();

    if (wv < 3) {
        const float* lw = last_w + wv * (HIDDEN + 17);
        float s = 0.f;
        for (int i = lane; i < HIDDEN + 17; i += 64) {
            float f;
            if (i < HIDDEN)          f = hbuf[i];
            else if (i < HIDDEN + 3) f = in_urls[b * 3 + (i - HIDDEN)];
            else                     f = other[b * 14 + (i - HIDDEN - 3)];
            s += lw[i] * f;
        }
        #pragma unroll
        for (int off = 32; off >= 1; off >>= 1) s += __shfl_xor(s, off);
        if (lane == 0) out[b * 3 + wv] = s + last_b[wv];
    }
}

// ============================ PROBES ========================================

// P1: pure dense-sweep read of X, 8 reps. Calibrates achievable read BW.
__global__ __launch_bounds__(256)
void xread_probe(const float* __restrict__ X, float* __restrict__ outp) {
    const int gsz = gridDim.x * 256;
    const int gid = blockIdx.x * 256 + threadIdx.x;
    const f32x4* X4 = (const f32x4*)X;
    f32x4 a = {0.f, 0.f, 0.f, 0.f};
    for (int rep = 0; rep < 8; ++rep) {
        for (int i = gid; i < 16777216; i += gsz)
            a += X4[i];
    }
    outp[gid] = a.x + a.y + a.z + a.w;
}

// P2: dots body x8, per-rep distinct outputs (no hoisting possible).
__global__ __launch_bounds__(256, 4)
void dots_probe(const float* __restrict__ X, const float* __restrict__ u,
                float* __restrict__ scr) {
    __shared__ float red[12];
    const int tid = threadIdx.x, lane = tid & 63, wv = tid >> 6;
    const f32x4 u0 = *(const f32x4*)(u + tid * 4);
    const f32x4 u1 = *(const f32x4*)(u + 1024 + tid * 4);
    const f32x4 u2 = *(const f32x4*)(u + 2048 + tid * 4);

    for (int rep = 0; rep < 8; ++rep) {
        float* d0 = scr + (size_t)rep * 196608;
        float* d1 = d0 + 65536;
        float* d2 = d1 + 65536;
        int row = blockIdx.x;
        f32x4 xA = *(const f32x4*)(X + (size_t)row * 1024 + tid * 4);
        f32x4 xB;
        #pragma unroll 4
        for (int i = 0; i < 16; ++i) {
            const int nrow = row + DG;
            if (i + 1 < 16)
                xB = *(const f32x4*)(X + (size_t)nrow * 1024 + tid * 4);
            float p0 = dp4(xA, u0), p1 = dp4(xA, u1), p2 = dp4(xA, u2);
            #pragma unroll
            for (int off = 32; off >= 1; off >>= 1) {
                p0 += __shfl_xor(p0, off);
                p1 += __shfl_xor(p1, off);
                p2 += __shfl_xor(p2, off);
            }
            if (lane == 0) {
                red[wv * 3 + 0] = p0; red[wv * 3 + 1] = p1; red[wv * 3 + 2] = p2;
            }
            __syncthreads();
            if (tid < 3) {
                const float s = red[tid] + red[3 + tid] + red[6 + tid] + red[9 + tid];
                float* dst = (tid == 0) ? d0 : (tid == 1) ? d1 : d2;
                dst[row] = s;
            }
            __syncthreads();
            xA = xB;
            row = nrow;
        }
        __syncthreads();
    }
}

// P3: span_acc body x8, per-rep distinct output regions.
__global__ __launch_bounds__(256, 4)
void span_acc_probe(const float* __restrict__ X, const float* __restrict__ C,
                    float* __restrict__ scr) {
    __shared__ float cs[256 * 12];
    __shared__ unsigned char flg[256];
    __shared__ int wany[4];
    __shared__ float rbuf[256 * 4];

    const int blk = blockIdx.x;
    const int b = blk >> 3, p = blk & 7;
    const int q = p >> 1, h = p & 1;
    const int tid = threadIdx.x, lane = tid & 63, wv = tid >> 6;

    for (int rep = 0; rep < 8; ++rep) {
        float* pb = scr + (size_t)rep * 2359296 + (size_t)blk * 2304;
        {
            const float* cp = C + ((size_t)b * 512 + h * 256) * 12;
            #pragma unroll
            for (int w = 0; w < 3; ++w)
                *(f32x4*)&cs[(tid + w * 256) * 4] = *(const f32x4*)(cp + (tid + w * 256) * 4);
        }
        __syncthreads();
        {
            const float* cr = &cs[tid * 12];
            float s = 0.f;
            #pragma unroll
            for (int j = 0; j < 12; ++j) s += fabsf(cr[j]);
            const bool f = (s != 0.f);
            flg[tid] = f ? 1 : 0;
            const unsigned long long m = __ballot(f);
            if (lane == 0) wany[wv] = (m != 0ull) ? 1 : 0;
        }
        __syncthreads();
        if ((wany[0] | wany[1] | wany[2] | wany[3]) == 0) {
            for (int i = tid; i < 2304; i += 256) pb[i] = 0.f;
            __syncthreads();
            continue;
        }

        f32x4 acc[9];
        #pragma unroll
        for (int a = 0; a < 9; ++a) acc[a] = (f32x4){0.f, 0.f, 0.f, 0.f};

        const float* Xw = X + ((size_t)b * 512 + h * 256 + wv * 64) * 1024 + q * 256 + lane * 4;
        const int rbase = wv * 64;

        for (int c = 0; c < 16; ++c) {
            const int r0 = rbase + c * 4;
            if ((flg[r0] | flg[r0 + 1] | flg[r0 + 2] | flg[r0 + 3]) == 0) continue;
            f32x4 x0 = *(const f32x4*)(Xw + (size_t)(c * 4 + 0) * 1024);
            f32x4 x1 = *(const f32x4*)(Xw + (size_t)(c * 4 + 1) * 1024);
            f32x4 x2 = *(const f32x4*)(Xw + (size_t)(c * 4 + 2) * 1024);
            f32x4 x3 = *(const f32x4*)(Xw + (size_t)(c * 4 + 3) * 1024);
            #define ROWFMA(xr, rr) { \
                f32x4 c0 = *(const f32x4*)&cs[(rr) * 12]; \
                f32x4 c1 = *(const f32x4*)&cs[(rr) * 12 + 4]; \
                f32x4 c2 = *(const f32x4*)&cs[(rr) * 12 + 8]; \
                acc[0] += c0.x * xr; acc[1] += c0.y * xr; acc[2] += c0.z * xr; \
                acc[3] += c1.x * xr; acc[4] += c1.y * xr; acc[5] += c1.z * xr; \
                acc[6] += c2.x * xr; acc[7] += c2.y * xr; acc[8] += c2.z * xr; }
            ROWFMA(x0, r0)
            ROWFMA(x1, r0 + 1)
            ROWFMA(x2, r0 + 2)
            ROWFMA(x3, r0 + 3)
            #undef ROWFMA
        }

        #pragma unroll
        for (int a = 0; a < 9; ++a) {
            __syncthreads();
            *(f32x4*)&rbuf[tid * 4] = acc[a];
            __syncthreads();
            if (tid < 64) {
                f32x4 s = *(const f32x4*)&rbuf[tid * 4];
                s += *(const f32x4*)&rbuf[(64 + tid) * 4];
                s += *(const f32x4*)&rbuf[(128 + tid) * 4];
                s += *(const f32x4*)&rbuf[(192 + tid) * 4];
                *(f32x4*)(pb + a * 256 + tid * 4) = s;
            }
        }
        __syncthreads();
    }
}

// P4: head body x16, writes scratch (NOT d_out).
__global__ __launch_bounds__(256)
void head_probe(const float* __restrict__ part, const float* __restrict__ Zv,
                const float* __restrict__ Wt2, const float* __restrict__ cb,
                const float* __restrict__ fcT,
                const float* __restrict__ in_urls, const float* __restrict__ other,
                const float* __restrict__ bn1_g, const float* __restrict__ bn1_b,
                const float* __restrict__ bn1_m, const float* __restrict__ bn1_v,
                const float* __restrict__ fc_b,
                const float* __restrict__ bn2_g, const float* __restrict__ bn2_b,
                const float* __restrict__ bn2_m, const float* __restrict__ bn2_v,
                const float* __restrict__ last_w, const float* __restrict__ last_b,
                float* __restrict__ scr) {
    __shared__ float yb[9 * 1024];
    __shared__ float emb[NSPANS * 64];
    __shared__ float hbuf[HIDDEN];

    const int b = blockIdx.x, tid = threadIdx.x, lane = tid & 63, wv = tid >> 6;

    for (int rep = 0; rep < 16; ++rep) {
        float* out = scr + rep * 384;
        {
            const int q = tid >> 6, pos = (tid & 63) * 4;
            const float* p0 = part + (size_t)(b * 8 + q * 2 + 0) * 2304 + pos;
            const float* p1 = part + (size_t)(b * 8 + q * 2 + 1) * 2304 + pos;
            #pragma unroll
            for (int i = 0; i < 9; ++i) {
                f32x4 v = *(const f32x4*)(p0 + i * 256) + *(const f32x4*)(p1 + i * 256);
                *(f32x4*)&yb[i * 1024 + q * 256 + pos] = v;
            }
        }
        __syncthreads();

        if (tid < 192) {
            const int s = tid >> 6, o = tid & 63;
            float a0 = 0.f, a1 = 0.f, a2 = 0.f, a3 = 0.f;
            #pragma unroll
            for (int t = 0; t < 3; ++t) {
                const float* wp = Wt2 + (size_t)t * 65536 + o;
                const float* yp = &yb[(s * 3 + t) * 1024];
                for (int k = 0; k < 1024; k += 4) {
                    a0 += wp[(size_t)(k + 0) * 64] * yp[k + 0];
                    a1 += wp[(size_t)(k + 1) * 64] * yp[k + 1];
                    a2 += wp[(size_t)(k + 2) * 64] * yp[k + 2];
                    a3 += wp[(size_t)(k + 3) * 64] * yp[k + 3];
                }
            }
            const float ev = (a0 + a1 + a2 + a3) / Zv[b * 3 + s] + cb[o];
            emb[tid] = (ev - bn1_m[tid]) * rsqrtf(bn1_v[tid] + 1e-5f) * bn1_g[tid] + bn1_b[tid];
        }
        __syncthreads();

        #pragma unroll
        for (int qq = 0; qq < 2; ++qq) {
            const int j = tid + qq * 256;
            float s = fc_b[j];
            #pragma unroll 4
            for (int i = 0; i < NSPANS * 64; ++i)
                s += fcT[(size_t)i * 512 + j] * emb[i];
            s = fmaxf(s, 0.f);
            hbuf[j] = (s - bn2_m[j]) * rsqrtf(bn2_v[j] + 1e-5f) * bn2_g[j] + bn2_b[j];
        }
        __syncthreads();

        if (wv < 3) {
            const float* lw = last_w + wv * (HIDDEN + 17);
            float s = 0.f;
            for (int i = lane; i < HIDDEN + 17; i += 64) {
                float f;
                if (i < HIDDEN)          f = hbuf[i];
                else if (i < HIDDEN + 3) f = in_urls[b * 3 + (i - HIDDEN)];
                else                     f = other[b * 14 + (i - HIDDEN - 3)];
                s += lw[i] * f;
            }
            #pragma unroll
            for (int off = 32; off >= 1; off >>= 1) s += __shfl_xor(s, off);
            if (lane == 0 && b == 0) out[b * 3 + wv] = s + last_b[wv];
        }
        __syncthreads();
    }
}

extern "C" void kernel_launch(void* const* d_in, const int* in_sizes, int n_in,
                              void* d_out, int out_size, void* d_ws, size_t ws_size,
                              hipStream_t stream) {
    const float* bert    = (const float*)d_in[0];
    const int*   offs    = (const int*)d_in[1];
    const float* in_urls = (const float*)d_in[2];
    const float* other   = (const float*)d_in[3];
    const float* conv_w  = (const float*)d_in[4];
    const float* conv_b  = (const float*)d_in[5];
    const float* att_w   = (const float*)d_in[6];
    const float* bn1_g   = (const float*)d_in[8];
    const float* bn1_b   = (const float*)d_in[9];
    const float* bn1_m   = (const float*)d_in[10];
    const float* bn1_v   = (const float*)d_in[11];
    const float* fc_w    = (const float*)d_in[12];
    const float* fc_b    = (const float*)d_in[13];
    const float* bn2_g   = (const float*)d_in[14];
    const float* bn2_b   = (const float*)d_in[15];
    const float* bn2_m   = (const float*)d_in[16];
    const float* bn2_v   = (const float*)d_in[17];
    const float* last_w  = (const float*)d_in[18];
    const float* last_b  = (const float*)d_in[19];

    float* u    = (float*)d_ws;
    float* Wt2  = (float*)((char*)d_ws + 12288);
    float* fcT  = (float*)((char*)d_ws + 798720);
    float* d0   = (float*)((char*)d_ws + 1191936);
    float* d1   = (float*)((char*)d_ws + 1454080);
    float* d2   = (float*)((char*)d_ws + 1716224);
    float* Zv   = (float*)((char*)d_ws + 1978368);
    float* C    = (float*)((char*)d_ws + 1979904);
    float* part = (float*)((char*)d_ws + 5125632);
    // probe scratch
    float* xscr = (float*)((char*)d_ws + 14562816);   // 2 MB
    float* dscr = (float*)((char*)d_ws + 16659968);   // 6 MB
    float* sscr = (float*)((char*)d_ws + 22951424);   // 75.5 MB
    float* hscr = (float*)((char*)d_ws + 98448896);   // 24 KB

    hipLaunchKernelGGL(prep_kernel, dim3(96), dim3(256), 0, stream,
                       conv_w, att_w, fc_w, u, Wt2, fcT);
    hipLaunchKernelGGL(dots_kernel, dim3(DG), dim3(256), 0, stream,
                       bert, u, d0, d1, d2);
    hipLaunchKernelGGL(coef_kernel, dim3(B_), dim3(256), 0, stream,
                       d0, d1, d2, offs, C, Zv);
    hipLaunchKernelGGL(span_acc_kernel, dim3(B_ * 8), dim3(256), 0, stream,
                       bert, C, part);
    // ---- probes (diagnostic only; outputs go to scratch) ----
    hipLaunchKernelGGL(xread_probe, dim3(2048), dim3(256), 0, stream, bert, xscr);
    hipLaunchKernelGGL(dots_probe, dim3(DG), dim3(256), 0, stream, bert, u, dscr);
    hipLaunchKernelGGL(span_acc_probe, dim3(B_ * 8), dim3(256), 0, stream,
                       bert, C, sscr);
    hipLaunchKernelGGL(head_probe, dim3(B_), dim3(256), 0, stream,
                       part, Zv, Wt2, conv_b, fcT, in_urls, other,
                       bn1_g, bn1_b, bn1_m, bn1_v, fc_b,
                       bn2_g, bn2_b, bn2_m, bn2_v, last_w, last_b, hscr);
    // ---- real head last (writes d_out) ----
    hipLaunchKernelGGL(head_kernel, dim3(B_), dim3(256), 0, stream,
                       part, Zv, Wt2, conv_b, fcT, in_urls, other,
                       bn1_g, bn1_b, bn1_m, bn1_v, fc_b,
                       bn2_g, bn2_b, bn2_m, bn2_v, last_w, last_b,
                       (float*)d_out);
}

// Round 11
// 166.864 us; speedup vs baseline: 24.0753x; 24.0753x over previous
//
#include <hip/hip_runtime.h>

// ---------------------------------------------------------------------------
// Head_87033217286245 — Round 11. R10 probes located the sink: head_kernel
// was 180us of the 216us total (0.5 block/CU, serial scalar-load dots,
// occupancy 5.9%). Head split into emb_kernel (384 blocks, lane-parallel-k,
// coalesced WtK) + fc_kernel (128 blocks x 512 threads). Streamers (36us
// combined, measured) kept R9-verbatim.
// ---------------------------------------------------------------------------

typedef float f32x4 __attribute__((ext_vector_type(4)));

#define B_      128
#define L_      512
#define NSPANS  3
#define HIDDEN  512
#define DG      4096

__device__ __forceinline__ float dp4(f32x4 a, f32x4 b) {
    return a.x*b.x + a.y*b.y + a.z*b.z + a.w*b.w;
}

// ---- k0: u_t[k]=Sum_o W[o,k,t]*aw[o]; WtK[t][o][k] (k contig); fcT[i][j]
__global__ __launch_bounds__(256)
void prep_kernel(const float* __restrict__ cw, const float* __restrict__ aw,
                 const float* __restrict__ fcw,
                 float* __restrict__ u, float* __restrict__ WtK,
                 float* __restrict__ fcT) {
    const int idx = blockIdx.x * 256 + threadIdx.x;
    if (idx < 3072) {
        const int t = idx >> 10, k = idx & 1023;
        float s = 0.f;
        #pragma unroll 8
        for (int o = 0; o < 64; ++o)
            s += cw[(size_t)(o * 1024 + k) * 3 + t] * aw[o];
        u[idx] = s;
    }
    for (int i = idx; i < 196608; i += 24576) {      // WtK[(t*64+o)*1024+k]
        const int k = i & 1023, r = i >> 10;
        const int o = r & 63, t = r >> 6;
        WtK[i] = cw[(size_t)(o * 1024 + k) * 3 + t];
    }
    for (int i = idx; i < 98304; i += 24576) {       // fcT[r*512+j]=fcw[j*192+r]
        const int j = i & 511, r = i >> 9;
        fcT[i] = fcw[(size_t)j * 192 + r];
    }
}

// ---- k1: dots (R9 verbatim)
__global__ __launch_bounds__(256, 4)
void dots_kernel(const float* __restrict__ X, const float* __restrict__ u,
                 float* __restrict__ d0, float* __restrict__ d1,
                 float* __restrict__ d2) {
    __shared__ float red[12];
    const int tid = threadIdx.x, lane = tid & 63, wv = tid >> 6;
    const f32x4 u0 = *(const f32x4*)(u + tid * 4);
    const f32x4 u1 = *(const f32x4*)(u + 1024 + tid * 4);
    const f32x4 u2 = *(const f32x4*)(u + 2048 + tid * 4);

    int row = blockIdx.x;
    f32x4 xA = *(const f32x4*)(X + (size_t)row * 1024 + tid * 4);
    f32x4 xB;
    #pragma unroll 4
    for (int i = 0; i < 16; ++i) {
        const int nrow = row + DG;
        if (i + 1 < 16)
            xB = *(const f32x4*)(X + (size_t)nrow * 1024 + tid * 4);
        float p0 = dp4(xA, u0), p1 = dp4(xA, u1), p2 = dp4(xA, u2);
        #pragma unroll
        for (int off = 32; off >= 1; off >>= 1) {
            p0 += __shfl_xor(p0, off);
            p1 += __shfl_xor(p1, off);
            p2 += __shfl_xor(p2, off);
        }
        if (lane == 0) {
            red[wv * 3 + 0] = p0; red[wv * 3 + 1] = p1; red[wv * 3 + 2] = p2;
        }
        __syncthreads();
        if (tid < 3) {
            const float s = red[tid] + red[3 + tid] + red[6 + tid] + red[9 + tid];
            float* dst = (tid == 0) ? d0 : (tid == 1) ? d1 : d2;
            dst[row] = s;
        }
        __syncthreads();
        xA = xB;
        row = nrow;
    }
}

// ---- k2: coef (R9 verbatim)
__global__ __launch_bounds__(256)
void coef_kernel(const float* __restrict__ d0, const float* __restrict__ d1,
                 const float* __restrict__ d2, const int* __restrict__ offs,
                 float* __restrict__ C, float* __restrict__ Zv) {
    __shared__ float lg[L_];
    __shared__ float red[4];
    const int b = blockIdx.x, tid = threadIdx.x, lane = tid & 63, wv = tid >> 6;
    const size_t g = (size_t)b * L_;

    for (int l = tid; l < L_; l += 256) {
        float v = d1[g + l];
        if (l >= 1)      v += d0[g + l - 1];
        if (l <= L_ - 2) v += d2[g + l + 1];
        lg[l] = v;
    }
    __syncthreads();

    float mxr[3]; int str[3], enr[3];
    for (int s = 0; s < 3; ++s) {
        const int st = offs[b * 6 + s * 2], en = offs[b * 6 + s * 2 + 1];
        str[s] = st; enr[s] = en;
        float mx = -1e30f;
        for (int l = st + tid; l <= en; l += 256) mx = fmaxf(mx, lg[l]);
        #pragma unroll
        for (int off = 32; off >= 1; off >>= 1) mx = fmaxf(mx, __shfl_xor(mx, off));
        if (lane == 0) red[wv] = mx;
        __syncthreads();
        mx = fmaxf(fmaxf(red[0], red[1]), fmaxf(red[2], red[3]));
        __syncthreads();
        float sm = 0.f;
        for (int l = st + tid; l <= en; l += 256) sm += __expf(lg[l] - mx);
        #pragma unroll
        for (int off = 32; off >= 1; off >>= 1) sm += __shfl_xor(sm, off);
        if (lane == 0) red[wv] = sm;
        __syncthreads();
        if (tid == 0) Zv[b * 3 + s] = red[0] + red[1] + red[2] + red[3];
        __syncthreads();
        mxr[s] = mx;
    }

    for (int m = tid; m < L_; m += 256) {
        f32x4 c[3];
        #pragma unroll
        for (int s = 0; s < 3; ++s) {
            #pragma unroll
            for (int t = 0; t < 3; ++t) {
                const int l  = m + 1 - t;
                const int li = min(max(l, 0), L_ - 1);
                c[s][t] = (l >= str[s] && l <= enr[s]) ? __expf(lg[li] - mxr[s]) : 0.f;
            }
            c[s][3] = 0.f;
        }
        float* cp = C + ((size_t)(g + m)) * 12;
        *(f32x4*)(cp)     = c[0];
        *(f32x4*)(cp + 4) = c[1];
        *(f32x4*)(cp + 8) = c[2];
    }
}

// ---- k3: span_acc (R9 verbatim)
__global__ __launch_bounds__(256, 4)
void span_acc_kernel(const float* __restrict__ X, const float* __restrict__ C,
                     float* __restrict__ part) {
    __shared__ float cs[256 * 12];
    __shared__ unsigned char flg[256];
    __shared__ int wany[4];
    __shared__ float rbuf[256 * 4];

    const int blk = blockIdx.x;
    const int b = blk >> 3, p = blk & 7;
    const int q = p >> 1, h = p & 1;
    const int tid = threadIdx.x, lane = tid & 63, wv = tid >> 6;
    float* pb = part + (size_t)blk * 2304;

    {
        const float* cp = C + ((size_t)b * 512 + h * 256) * 12;
        #pragma unroll
        for (int w = 0; w < 3; ++w)
            *(f32x4*)&cs[(tid + w * 256) * 4] = *(const f32x4*)(cp + (tid + w * 256) * 4);
    }
    __syncthreads();
    {
        const float* cr = &cs[tid * 12];
        float s = 0.f;
        #pragma unroll
        for (int j = 0; j < 12; ++j) s += fabsf(cr[j]);
        const bool f = (s != 0.f);
        flg[tid] = f ? 1 : 0;
        const unsigned long long m = __ballot(f);
        if (lane == 0) wany[wv] = (m != 0ull) ? 1 : 0;
    }
    __syncthreads();
    if ((wany[0] | wany[1] | wany[2] | wany[3]) == 0) {
        for (int i = tid; i < 2304; i += 256) pb[i] = 0.f;
        return;
    }

    f32x4 acc[9];
    #pragma unroll
    for (int a = 0; a < 9; ++a) acc[a] = (f32x4){0.f, 0.f, 0.f, 0.f};

    const float* Xw = X + ((size_t)b * 512 + h * 256 + wv * 64) * 1024 + q * 256 + lane * 4;
    const int rbase = wv * 64;

    for (int c = 0; c < 16; ++c) {
        const int r0 = rbase + c * 4;
        if ((flg[r0] | flg[r0 + 1] | flg[r0 + 2] | flg[r0 + 3]) == 0) continue;
        f32x4 x0 = *(const f32x4*)(Xw + (size_t)(c * 4 + 0) * 1024);
        f32x4 x1 = *(const f32x4*)(Xw + (size_t)(c * 4 + 1) * 1024);
        f32x4 x2 = *(const f32x4*)(Xw + (size_t)(c * 4 + 2) * 1024);
        f32x4 x3 = *(const f32x4*)(Xw + (size_t)(c * 4 + 3) * 1024);
        #define ROWFMA(xr, rr) { \
            f32x4 c0 = *(const f32x4*)&cs[(rr) * 12]; \
            f32x4 c1 = *(const f32x4*)&cs[(rr) * 12 + 4]; \
            f32x4 c2 = *(const f32x4*)&cs[(rr) * 12 + 8]; \
            acc[0] += c0.x * xr; acc[1] += c0.y * xr; acc[2] += c0.z * xr; \
            acc[3] += c1.x * xr; acc[4] += c1.y * xr; acc[5] += c1.z * xr; \
            acc[6] += c2.x * xr; acc[7] += c2.y * xr; acc[8] += c2.z * xr; }
        ROWFMA(x0, r0)
        ROWFMA(x1, r0 + 1)
        ROWFMA(x2, r0 + 2)
        ROWFMA(x3, r0 + 3)
        #undef ROWFMA
    }

    #pragma unroll
    for (int a = 0; a < 9; ++a) {
        __syncthreads();
        *(f32x4*)&rbuf[tid * 4] = acc[a];
        __syncthreads();
        if (tid < 64) {
            f32x4 s = *(const f32x4*)&rbuf[tid * 4];
            s += *(const f32x4*)&rbuf[(64 + tid) * 4];
            s += *(const f32x4*)&rbuf[(128 + tid) * 4];
            s += *(const f32x4*)&rbuf[(192 + tid) * 4];
            *(f32x4*)(pb + a * 256 + tid * 4) = s;
        }
    }
}

// ---- k4: emb. Grid (b*3+s)=384. Wave w -> 16 outputs, lane-parallel over k.
// embb[b*192 + s*64 + o] = BN1( (Sum_t,k WtK[t][o][k]*yb[t][k]) / Z + cb[o] )
__global__ __launch_bounds__(256)
void emb_kernel(const float* __restrict__ part, const float* __restrict__ Zv,
                const float* __restrict__ WtK, const float* __restrict__ cb,
                const float* __restrict__ bn1_g, const float* __restrict__ bn1_b,
                const float* __restrict__ bn1_m, const float* __restrict__ bn1_v,
                float* __restrict__ embb) {
    __shared__ float yls[3 * 1024];      // 12 KB

    const int bs = blockIdx.x;
    const int b = bs / 3, s = bs - b * 3;
    const int tid = threadIdx.x, lane = tid & 63, wv = tid >> 6;

    {   // yb[t][k] = part[h=0] + part[h=1], k = q*256 + pos
        const int q = tid >> 6, pos = (tid & 63) * 4;
        const float* p0 = part + (size_t)(b * 8 + q * 2 + 0) * 2304 + pos;
        const float* p1 = part + (size_t)(b * 8 + q * 2 + 1) * 2304 + pos;
        #pragma unroll
        for (int t = 0; t < 3; ++t) {
            const int i = s * 3 + t;
            f32x4 v = *(const f32x4*)(p0 + i * 256) + *(const f32x4*)(p1 + i * 256);
            *(f32x4*)&yls[t * 1024 + q * 256 + pos] = v;
        }
    }
    __syncthreads();

    const float Zinv = 1.f / Zv[b * 3 + s];
    #pragma unroll 2
    for (int oi = 0; oi < 16; ++oi) {
        const int o = wv * 16 + oi;
        float acc = 0.f;
        #pragma unroll
        for (int t = 0; t < 3; ++t) {
            const float* w = WtK + (size_t)(t * 64 + o) * 1024 + lane * 4;
            const float* y = &yls[t * 1024 + lane * 4];
            #pragma unroll
            for (int st = 0; st < 4; ++st)
                acc += dp4(*(const f32x4*)(w + st * 256), *(const f32x4*)(y + st * 256));
        }
        #pragma unroll
        for (int off = 32; off >= 1; off >>= 1) acc += __shfl_xor(acc, off);
        if (lane == 0) {
            const float ev = acc * Zinv + cb[o];
            const int i = s * 64 + o;
            embb[(size_t)b * 192 + i] =
                (ev - bn1_m[i]) * rsqrtf(bn1_v[i] + 1e-5f) * bn1_g[i] + bn1_b[i];
        }
    }
}

// ---- k5: fc + last. 128 blocks x 512 threads (thread-per-j, 8 waves).
__global__ __launch_bounds__(512)
void fc_kernel(const float* __restrict__ embb, const float* __restrict__ fcT,
               const float* __restrict__ in_urls, const float* __restrict__ other,
               const float* __restrict__ fc_b,
               const float* __restrict__ bn2_g, const float* __restrict__ bn2_b,
               const float* __restrict__ bn2_m, const float* __restrict__ bn2_v,
               const float* __restrict__ last_w, const float* __restrict__ last_b,
               float* __restrict__ out) {
    __shared__ float embL[192];
    __shared__ float hbuf[HIDDEN];

    const int b = blockIdx.x, tid = threadIdx.x, lane = tid & 63, wv = tid >> 6;

    if (tid < 192) embL[tid] = embb[(size_t)b * 192 + tid];
    __syncthreads();

    {
        const int j = tid;
        float s = fc_b[j];
        #pragma unroll 8
        for (int i = 0; i < 192; ++i)
            s += fcT[(size_t)i * 512 + j] * embL[i];          // j coalesced
        s = fmaxf(s, 0.f);
        hbuf[j] = (s - bn2_m[j]) * rsqrtf(bn2_v[j] + 1e-5f) * bn2_g[j] + bn2_b[j];
    }
    __syncthreads();

    if (wv < 3) {
        const float* lw = last_w + wv * (HIDDEN + 17);
        float s = 0.f;
        for (int i = lane; i < HIDDEN + 17; i += 64) {
            float f;
            if (i < HIDDEN)          f = hbuf[i];
            else if (i < HIDDEN + 3) f = in_urls[b * 3 + (i - HIDDEN)];
            else                     f = other[b * 14 + (i - HIDDEN - 3)];
            s += lw[i] * f;
        }
        #pragma unroll
        for (int off = 32; off >= 1; off >>= 1) s += __shfl_xor(s, off);
        if (lane == 0) out[b * 3 + wv] = s + last_b[wv];
    }
}

extern "C" void kernel_launch(void* const* d_in, const int* in_sizes, int n_in,
                              void* d_out, int out_size, void* d_ws, size_t ws_size,
                              hipStream_t stream) {
    const float* bert    = (const float*)d_in[0];
    const int*   offs    = (const int*)d_in[1];
    const float* in_urls = (const float*)d_in[2];
    const float* other   = (const float*)d_in[3];
    const float* conv_w  = (const float*)d_in[4];
    const float* conv_b  = (const float*)d_in[5];
    const float* att_w   = (const float*)d_in[6];
    const float* bn1_g   = (const float*)d_in[8];
    const float* bn1_b   = (const float*)d_in[9];
    const float* bn1_m   = (const float*)d_in[10];
    const float* bn1_v   = (const float*)d_in[11];
    const float* fc_w    = (const float*)d_in[12];
    const float* fc_b    = (const float*)d_in[13];
    const float* bn2_g   = (const float*)d_in[14];
    const float* bn2_b   = (const float*)d_in[15];
    const float* bn2_m   = (const float*)d_in[16];
    const float* bn2_v   = (const float*)d_in[17];
    const float* last_w  = (const float*)d_in[18];
    const float* last_b  = (const float*)d_in[19];

    float* u    = (float*)d_ws;
    float* WtK  = (float*)((char*)d_ws + 12288);
    float* fcT  = (float*)((char*)d_ws + 798720);
    float* d0   = (float*)((char*)d_ws + 1191936);
    float* d1   = (float*)((char*)d_ws + 1454080);
    float* d2   = (float*)((char*)d_ws + 1716224);
    float* Zv   = (float*)((char*)d_ws + 1978368);
    float* C    = (float*)((char*)d_ws + 1979904);
    float* part = (float*)((char*)d_ws + 5125632);
    float* embb = (float*)((char*)d_ws + 14562816);

    hipLaunchKernelGGL(prep_kernel, dim3(96), dim3(256), 0, stream,
                       conv_w, att_w, fc_w, u, WtK, fcT);
    hipLaunchKernelGGL(dots_kernel, dim3(DG), dim3(256), 0, stream,
                       bert, u, d0, d1, d2);
    hipLaunchKernelGGL(coef_kernel, dim3(B_), dim3(256), 0, stream,
                       d0, d1, d2, offs, C, Zv);
    hipLaunchKernelGGL(span_acc_kernel, dim3(B_ * 8), dim3(256), 0, stream,
                       bert, C, part);
    hipLaunchKernelGGL(emb_kernel, dim3(B_ * NSPANS), dim3(256), 0, stream,
                       part, Zv, WtK, conv_b, bn1_g, bn1_b, bn1_m, bn1_v, embb);
    hipLaunchKernelGGL(fc_kernel, dim3(B_), dim3(512), 0, stream,
                       embb, fcT, in_urls, other, fc_b,
                       bn2_g, bn2_b, bn2_m, bn2_v, last_w, last_b,
                       (float*)d_out);
}